// Round 14
// baseline (169.312 us; speedup 1.0000x reference)
//
#include <hip/hip_runtime.h>
#include <hip/hip_bf16.h>

#define S_LEN   2048
#define HID     1024
#define NH      16
#define HD      64
#define WIN     512
#define NW      4
#define NG      64
#define GSTRIDE 32
#define SCALE   0.125f               // 64^-0.5
#define SCALE_LOG2E 0.180336880f    // 0.125 * log2(e)

#if __has_builtin(__builtin_amdgcn_exp2f)
#define EXP2F(x) __builtin_amdgcn_exp2f(x)
#else
#define EXP2F(x) __expf((x) * 0.6931471805599453f)
#endif

typedef __bf16 bf16x2 __attribute__((ext_vector_type(2)));
typedef __bf16 bf16x8 __attribute__((ext_vector_type(8)));
typedef float  f32x4  __attribute__((ext_vector_type(4)));
typedef unsigned short ushort_t;

// ---------------- fp32 -> bf16 helpers ----------------
__device__ __forceinline__ ushort_t f32_to_bf16_rne(float f) {
    unsigned int u = __float_as_uint(f);
    u = u + 0x7FFFu + ((u >> 16) & 1u);
    return (ushort_t)(u >> 16);
}
__device__ __forceinline__ float bf16_to_f32(ushort_t h) {
    return __uint_as_float(((unsigned int)h) << 16);
}
// packed conversion: gfx950 HW v_cvt_pk_bf16_f32 (RNE), 2 values/instruction
#if __has_builtin(__builtin_amdgcn_cvt_pk_bf16_f32)
__device__ __forceinline__ unsigned int pk_bf16(float a, float b) {
    bf16x2 t = __builtin_amdgcn_cvt_pk_bf16_f32(a, b);
    return __builtin_bit_cast(unsigned int, t);
}
#else
__device__ __forceinline__ unsigned int pk_bf16(float a, float b) {
    return (unsigned int)f32_to_bf16_rne(a) | ((unsigned int)f32_to_bf16_rne(b) << 16);
}
#endif

// ---------------- batched cast: 5 tensors fp32 -> bf16 in one launch ----------------
struct CastJobs {
    const float* in[5];
    ushort_t* hi[5];
    int n4[5];
};

__global__ __launch_bounds__(256) void cast_all_kernel(CastJobs jobs) {
    int j = blockIdx.y;
    int i = blockIdx.x * 256 + threadIdx.x;
    if (i >= jobs.n4[j]) return;
    float4 f = ((const float4*)jobs.in[j])[i];
    uint2 h;
    h.x = pk_bf16(f.x, f.y);
    h.y = pk_bf16(f.z, f.w);
    ((uint2*)jobs.hi[j])[i] = h;
}

// ---------------- async global -> LDS (16B per lane) ----------------
__device__ __forceinline__ void async16(const ushort_t* g, ushort_t* l) {
    __builtin_amdgcn_global_load_lds(
        (const __attribute__((address_space(1))) void*)g,
        (__attribute__((address_space(3))) void*)l, 16, 0, 0);
}

// ============== SINGLE-WAVE MFMA GEMM, barrier-free double-buffered ==============
// Each block = ONE wave owning the full tile, so no __syncthreads is ever
// needed: the wave's own global_load_lds -> ds_read dependency is handled by
// s_waitcnt vmcnt(N). True 1-deep pipeline: issue tile k+1's loads, wait
// vmcnt(<count>) (tile k's loads done, k+1's still in flight), compute tile k.
// This is the fine-grained-vmcnt pattern the 2-barrier structure couldn't
// express (R7/m131 lesson: cross-wave barriers force a drain; here there is
// no second wave). LDS staging keeps global reads coalesced (R10 lesson).

// --- QKV: 128x64 tile per wave, BK=64, grid (3 segs x 16 cols) x 16 rows = 768 ---
// LDS 2x(16+8) = 48 KB -> 3 blocks/CU = 3 waves/CU. 24 async16/lane per tile.
// q output PRE-SCALED by SCALE*log2e (its only consumers want scaled scores).
__global__ __launch_bounds__(64) void gemm_qkv_kernel(
    const ushort_t* __restrict__ xb,
    const ushort_t* __restrict__ wqb, const float* __restrict__ bq,
    const ushort_t* __restrict__ wkb, const float* __restrict__ bk,
    const ushort_t* __restrict__ wvb, const float* __restrict__ bv,
    ushort_t* __restrict__ qb, ushort_t* __restrict__ kb,
    ushort_t* __restrict__ vtb)
{
    __shared__ ushort_t sA[2][128 * 64];   // 2 x 16 KB
    __shared__ ushort_t sB[2][64 * 64];    // 2 x  8 KB
    const int lane = threadIdx.x;
    const int quad = lane >> 4, lm = lane & 15;
    const int seg  = blockIdx.x >> 4;
    const int bn   = (blockIdx.x & 15) * 64;
    const int bm   = blockIdx.y * 128;

    const ushort_t* B  = (seg == 0) ? wqb : (seg == 1) ? wkb : wvb;
    const float* bias  = (seg == 0) ? bq  : (seg == 1) ? bk  : bv;

    f32x4 acc[8][4];
#pragma unroll
    for (int i = 0; i < 8; ++i)
#pragma unroll
        for (int j = 0; j < 4; ++j) acc[i][j] = {0.f, 0.f, 0.f, 0.f};

    // prologue: stage tile 0 into buffer 0
#pragma unroll
    for (int t = 0; t < 16; ++t) {         // A: 1024 chunks, 16/lane
        int c = lane + t * 64;
        int row = c >> 3, kp = c & 7, gc = kp ^ (row & 7);
        async16(&xb[(size_t)(bm + row) * HID + gc * 8], &sA[0][c * 8]);
    }
#pragma unroll
    for (int t = 0; t < 8; ++t) {          // B: 512 chunks, 8/lane
        int c = lane + t * 64;
        int row = c >> 3, kp = c & 7, gc = kp ^ (row & 7);
        async16(&B[(size_t)(bn + row) * HID + gc * 8], &sB[0][c * 8]);
    }

    for (int it = 0; it < 16; ++it) {
        if (it < 15) {
            int k1 = (it + 1) * 64, b = (it + 1) & 1;
#pragma unroll
            for (int t = 0; t < 16; ++t) {
                int c = lane + t * 64;
                int row = c >> 3, kp = c & 7, gc = kp ^ (row & 7);
                async16(&xb[(size_t)(bm + row) * HID + k1 + gc * 8], &sA[b][c * 8]);
            }
#pragma unroll
            for (int t = 0; t < 8; ++t) {
                int c = lane + t * 64;
                int row = c >> 3, kp = c & 7, gc = kp ^ (row & 7);
                async16(&B[(size_t)(bn + row) * HID + k1 + gc * 8], &sB[b][c * 8]);
            }
            // wait for THIS tile's 24 loads (prev iter's issue); next 24 stay in flight
            asm volatile("s_waitcnt vmcnt(24)" ::: "memory");
        } else {
            asm volatile("s_waitcnt vmcnt(0)" ::: "memory");
        }
        const ushort_t* cA = sA[it & 1];
        const ushort_t* cB = sB[it & 1];
#pragma unroll
        for (int sub = 0; sub < 2; ++sub) {
            bf16x8 af[8], bf[4];
#pragma unroll
            for (int i = 0; i < 8; ++i) {
                int row = i * 16 + lm;
                int slot = (sub * 4 + quad) ^ (row & 7);
                af[i] = *(const bf16x8*)&cA[row * 64 + slot * 8];
            }
#pragma unroll
            for (int j = 0; j < 4; ++j) {
                int row = j * 16 + lm;
                int slot = (sub * 4 + quad) ^ (row & 7);
                bf[j] = *(const bf16x8*)&cB[row * 64 + slot * 8];
            }
#pragma unroll
            for (int i = 0; i < 8; ++i)
#pragma unroll
                for (int j = 0; j < 4; ++j)
                    acc[i][j] = __builtin_amdgcn_mfma_f32_16x16x32_bf16(af[i], bf[j], acc[i][j], 0, 0, 0);
        }
    }

    // epilogue: C/D layout col=lane&15, row=quad*4+reg
    const float qsc = (seg == 0) ? SCALE_LOG2E : 1.0f;
#pragma unroll
    for (int i = 0; i < 8; ++i)
#pragma unroll
        for (int j = 0; j < 4; ++j) {
            int col = bn + j * 16 + lm;
            float b = bias[col];
            int row0 = bm + i * 16 + quad * 4;
            if (seg == 2) {
                // transposed V: r=0..3 are consecutive jj -> one 8B store
                int hh = col >> 6, dd = col & 63, nn = row0 >> 9, jj = row0 & 511;
                uint2 v4;
                v4.x = pk_bf16(acc[i][j][0] + b, acc[i][j][1] + b);
                v4.y = pk_bf16(acc[i][j][2] + b, acc[i][j][3] + b);
                *(uint2*)&vtb[(((size_t)nn * NH + hh) * HD + dd) * WIN + jj] = v4;
            } else {
                ushort_t* dst = (seg == 0) ? qb : kb;
                unsigned int c01 = pk_bf16((acc[i][j][0] + b) * qsc, (acc[i][j][1] + b) * qsc);
                unsigned int c23 = pk_bf16((acc[i][j][2] + b) * qsc, (acc[i][j][3] + b) * qsc);
                dst[(size_t)(row0 + 0) * HID + col] = (ushort_t)(c01 & 0xFFFFu);
                dst[(size_t)(row0 + 1) * HID + col] = (ushort_t)(c01 >> 16);
                dst[(size_t)(row0 + 2) * HID + col] = (ushort_t)(c23 & 0xFFFFu);
                dst[(size_t)(row0 + 3) * HID + col] = (ushort_t)(c23 >> 16);
            }
        }
}

// --- out-proj: 64x64 tile per wave, BK=64, grid 16x32 = 512 blocks ---
// LDS 2x(8+8) = 32 KB; 16 async16/lane per tile -> vmcnt(16) pipeline.
__global__ __launch_bounds__(64) void gemm_out_kernel(
    const ushort_t* __restrict__ A, const ushort_t* __restrict__ B,
    const float* __restrict__ bias, float* __restrict__ out)
{
    __shared__ ushort_t sA[2][64 * 64];   // 2 x 8 KB
    __shared__ ushort_t sB[2][64 * 64];   // 2 x 8 KB
    const int lane = threadIdx.x;
    const int quad = lane >> 4, lm = lane & 15;
    const int bn   = blockIdx.x * 64;
    const int bm   = blockIdx.y * 64;

    f32x4 acc[4][4];
#pragma unroll
    for (int i = 0; i < 4; ++i)
#pragma unroll
        for (int j = 0; j < 4; ++j) acc[i][j] = {0.f, 0.f, 0.f, 0.f};

#pragma unroll
    for (int t = 0; t < 8; ++t) {
        int c = lane + t * 64;
        int row = c >> 3, kp = c & 7, gc = kp ^ (row & 7);
        async16(&A[(size_t)(bm + row) * HID + gc * 8], &sA[0][c * 8]);
        async16(&B[(size_t)(bn + row) * HID + gc * 8], &sB[0][c * 8]);
    }

    for (int it = 0; it < 16; ++it) {
        if (it < 15) {
            int k1 = (it + 1) * 64, b = (it + 1) & 1;
#pragma unroll
            for (int t = 0; t < 8; ++t) {
                int c = lane + t * 64;
                int row = c >> 3, kp = c & 7, gc = kp ^ (row & 7);
                async16(&A[(size_t)(bm + row) * HID + k1 + gc * 8], &sA[b][c * 8]);
                async16(&B[(size_t)(bn + row) * HID + k1 + gc * 8], &sB[b][c * 8]);
            }
            asm volatile("s_waitcnt vmcnt(16)" ::: "memory");
        } else {
            asm volatile("s_waitcnt vmcnt(0)" ::: "memory");
        }
        const ushort_t* cA = sA[it & 1];
        const ushort_t* cB = sB[it & 1];
#pragma unroll
        for (int sub = 0; sub < 2; ++sub) {
            bf16x8 af[4], bf[4];
#pragma unroll
            for (int i = 0; i < 4; ++i) {
                int row = i * 16 + lm;
                int slot = (sub * 4 + quad) ^ (row & 7);
                af[i] = *(const bf16x8*)&cA[row * 64 + slot * 8];
            }
#pragma unroll
            for (int j = 0; j < 4; ++j) {
                int row = j * 16 + lm;
                int slot = (sub * 4 + quad) ^ (row & 7);
                bf[j] = *(const bf16x8*)&cB[row * 64 + slot * 8];
            }
#pragma unroll
            for (int i = 0; i < 4; ++i)
#pragma unroll
                for (int j = 0; j < 4; ++j)
                    acc[i][j] = __builtin_amdgcn_mfma_f32_16x16x32_bf16(af[i], bf[j], acc[i][j], 0, 0, 0);
        }
    }

#pragma unroll
    for (int i = 0; i < 4; ++i)
#pragma unroll
        for (int j = 0; j < 4; ++j) {
            int col = bn + j * 16 + lm;
            float b = bias[col];
#pragma unroll
            for (int r = 0; r < 4; ++r) {
                int row = bm + i * 16 + quad * 4 + r;
                out[(size_t)row * HID + col] = acc[i][j][r] + b;
            }
        }
}

// ---------------- V sums from transposed bf16 V: wave per (n,h,d) row ----------------
__global__ __launch_bounds__(256) void vsum_kernel(const ushort_t* __restrict__ vtb,
    float* __restrict__ vwin, float* __restrict__ vgwin)
{
    int wid  = blockIdx.x * 4 + (threadIdx.x >> 6);   // 0..4095 = (n*NH+h)*HD+d
    int lane = threadIdx.x & 63;
    bf16x8 v = *(const bf16x8*)&vtb[(size_t)wid * WIN + lane * 8];
    float s = 0.f;
#pragma unroll
    for (int e = 0; e < 8; ++e) s += (float)v[e];
    float sg = ((lane & 3) == 0) ? (float)v[0] : 0.f;  // j = lane*8, j%32==0 iff lane%4==0
#pragma unroll
    for (int off = 1; off < 64; off <<= 1) {
        s  += __shfl_xor(s,  off);
        sg += __shfl_xor(sg, off);
    }
    if (lane == 0) { vwin[wid] = s; vgwin[wid] = sg; }
}

// ---------------- MFMA flash attention (R13, unchanged) ----------------
__global__ __launch_bounds__(128) void attn_mfma_kernel(
    const ushort_t* __restrict__ qb, const ushort_t* __restrict__ kb,
    const ushort_t* __restrict__ vtb,
    const float* __restrict__ vwin, const float* __restrict__ vgwin,
    ushort_t* __restrict__ ath)
{
    __shared__ __align__(16) ushort_t sK[64 * 64];    // [key][8 chunks of 8 d], swizzled
    __shared__ __align__(16) ushort_t sVt[64 * 64];   // [d][8 chunks of 8 j], swizzled
    __shared__ __align__(16) ushort_t sP[2][16 * 68]; // per-wave P[q][key], 68-padded rows
    __shared__ float sPe[48];
    __shared__ float sAe[64];
    __shared__ float sLe0;

    const int tid  = threadIdx.x;
    const int lane = tid & 63;
    const int w    = tid >> 6;     // 0..1
    const int quad = lane >> 4;
    const int lm   = lane & 15;
    const int tile = blockIdx.x;   // 0..15
    const int h    = blockIdx.y;
    const int n    = blockIdx.z;

    const ushort_t* kbase = &kb[(size_t)(n * WIN) * HID + h * HD];
    const ushort_t* vbase = &vtb[(size_t)(n * NH + h) * HD * WIN];

    const size_t qrow = (size_t)(n * WIN + tile * 32 + w * 16 + lm);
    const bf16x8 aq0 = *(const bf16x8*)&qb[qrow * HID + h * HD + quad * 8];
    const bf16x8 aq1 = *(const bf16x8*)&qb[qrow * HID + h * HD + 32 + quad * 8];

    f32x4 acc[4];
#pragma unroll
    for (int dt = 0; dt < 4; ++dt) acc[dt] = {0.f, 0.f, 0.f, 0.f};
    float lac = 0.f;                       // denominator partial for query lm
    const bool qgl = (w == 0) && (lm == 0);

    ushort_t* sPw = sP[w];

    for (int c = 0; c < 8; ++c) {
        __syncthreads();
#pragma unroll
        for (int t = 0; t < 4; ++t) {
            int c2 = tid + t * 128;
            int key = c2 >> 3, ck = c2 & 7, gc = ck ^ (key & 7);
            async16(&kbase[(size_t)(c * 64 + key) * HID + gc * 8], &sK[c2 * 8]);
            int dd = c2 >> 3, sl = c2 & 7, gj = sl ^ (dd & 7);
            async16(&vbase[(size_t)dd * WIN + c * 64 + gj * 8], &sVt[c2 * 8]);
        }
        asm volatile("s_waitcnt vmcnt(0)" ::: "memory");
        __syncthreads();

        // ---- S^T = K.Q^T + softmax numerators (shift m=0 safe: |s| < ~4) ----
#pragma unroll
        for (int jt = 0; jt < 4; ++jt) {
            int key = jt * 16 + lm;
            bf16x8 ak0 = *(const bf16x8*)&sK[key * 64 + ((quad) ^ (key & 7)) * 8];
            bf16x8 ak1 = *(const bf16x8*)&sK[key * 64 + ((4 + quad) ^ (key & 7)) * 8];
            f32x4 s = {0.f, 0.f, 0.f, 0.f};
            s = __builtin_amdgcn_mfma_f32_16x16x32_bf16(ak0, aq0, s, 0, 0, 0);
            s = __builtin_amdgcn_mfma_f32_16x16x32_bf16(ak1, aq1, s, 0, 0, 0);
            const bool kg = ((jt & 1) == 0) && (quad == 0);
            float p[4];
#pragma unroll
            for (int r = 0; r < 4; ++r) {
                float sv = s[r];
                if (qgl && kg && r == 0) sv += sv;
                p[r] = EXP2F(sv);
                lac += p[r];
            }
            uint2 pp;
            pp.x = pk_bf16(p[0], p[1]);
            pp.y = pk_bf16(p[2], p[3]);
            *(uint2*)&sPw[lm * 68 + jt * 16 + quad * 4] = pp;
        }

        // ---- PV ----
        bf16x8 pf[2];
        pf[0] = *(const bf16x8*)&sPw[lm * 68 + quad * 8];
        pf[1] = *(const bf16x8*)&sPw[lm * 68 + 32 + quad * 8];
#pragma unroll
        for (int dt = 0; dt < 4; ++dt) {
            int d = dt * 16 + lm;
#pragma unroll
            for (int jc = 0; jc < 2; ++jc) {
                bf16x8 vf = *(const bf16x8*)&sVt[d * 64 + (((jc * 4 + quad) ^ (d & 7))) * 8];
                acc[dt] = __builtin_amdgcn_mfma_f32_16x16x32_bf16(pf[jc], vf, acc[dt], 0, 0, 0);
            }
        }
    }

    float lred = lac;
    lred += __shfl_xor(lred, 16);
    lred += __shfl_xor(lred, 32);

    __syncthreads();
    if (tid < 48) {
        int kk = tid;
        int g = kk + (kk >= n * 16 ? 16 : 0);
        const ushort_t* qr = &qb[(size_t)(n * WIN + tile * 32) * HID + h * HD];
        const ushort_t* kr = &kb[(size_t)(g * GSTRIDE) * HID + h * HD];
        float dot = 0.f;
#pragma unroll
        for (int dc = 0; dc < 8; ++dc) {
            bf16x8 qv = *(const bf16x8*)&qr[dc * 8];
            bf16x8 kv = *(const bf16x8*)&kr[dc * 8];
#pragma unroll
            for (int e = 0; e < 8; ++e) dot += (float)qv[e] * (float)kv[e];
        }
        sPe[tid] = EXP2F(dot);    // q pre-scaled by SCALE*log2e
    }
    __syncthreads();
    if (tid < 64) {
        int d = tid;
        float a = 0.f;
        for (int kk = 0; kk < 48; ++kk) {
            int g = kk + (kk >= n * 16 ? 16 : 0);
            int gwin = g >> 4, jj = (g & 15) * GSTRIDE;
            a += sPe[kk] *
                 bf16_to_f32(vtb[((size_t)(gwin * NH + h) * HD + d) * WIN + jj]);
        }
        sAe[d] = a;
    } else if (tid == 64) {
        float s = 0.f;
        for (int kk = 0; kk < 48; ++kk) s += sPe[kk];
        sLe0 = s;
    }
    __syncthreads();

    float vr_ng_r[4], vr_g_r[4];
#pragma unroll
    for (int dt = 0; dt < 4; ++dt) {
        int d = dt * 16 + lm;
        float vall = 0.f, vgall = 0.f;
#pragma unroll
        for (int n2 = 0; n2 < NW; ++n2) {
            vall  += vwin [(n2 * NH + h) * HD + d];
            vgall += vgwin[(n2 * NH + h) * HD + d];
        }
        float w_  = vwin [(n * NH + h) * HD + d];
        float gw_ = vgwin[(n * NH + h) * HD + d];
        vr_ng_r[dt] = vall - w_;
        vr_g_r[dt]  = vall - w_ - (vgall - gw_);
    }

#pragma unroll
    for (int r = 0; r < 4; ++r) {
        int qo = w * 16 + quad * 4 + r;
        int qwin = tile * 32 + qo;
        bool isg = ((qwin & (GSTRIDE - 1)) == 0);
        float lr = __shfl(lred, quad * 4 + r);
        float l = lr + (float)(S_LEN - WIN);
        if (isg) l += sLe0 - 48.0f;
        float invl = 1.f / l;
        size_t row = (size_t)(n * WIN + qwin) * HID + h * HD;
#pragma unroll
        for (int dt = 0; dt < 4; ++dt) {
            int d = dt * 16 + lm;
            float o = acc[dt][r] + (isg ? (vr_g_r[dt] + sAe[d]) : vr_ng_r[dt]);
            ath[row + d] = f32_to_bf16_rne(o * invl);
        }
    }
}

extern "C" void kernel_launch(void* const* d_in, const int* in_sizes, int n_in,
                              void* d_out, int out_size, void* d_ws, size_t ws_size,
                              hipStream_t stream) {
    const float* x   = (const float*)d_in[0];
    const float* wq  = (const float*)d_in[1];
    const float* bq  = (const float*)d_in[2];
    const float* wk  = (const float*)d_in[3];
    const float* bk_ = (const float*)d_in[4];
    const float* wv  = (const float*)d_in[5];
    const float* bv  = (const float*)d_in[6];
    const float* wo  = (const float*)d_in[7];
    const float* bo  = (const float*)d_in[8];
    float* out = (float*)d_out;

    const size_t M2 = 2u * 1024 * 1024, M1 = 1024 * 1024;
    float* ws = (float*)d_ws;
    float* vwin  = ws;                       // 4096 floats
    float* vgwin = vwin + NW * NH * HD;      // 4096 floats
    ushort_t* us = (ushort_t*)(ws + 16384);
    ushort_t* xb  = us;            // 4 MB
    ushort_t* wqb = xb + M2;       ushort_t* wkb = wqb + M1;
    ushort_t* wvb = wkb + M1;      ushort_t* wob = wvb + M1;
    ushort_t* qb  = wob + M1;      // 4 MB
    ushort_t* kb  = qb + M2;       // 4 MB
    ushort_t* vtb = kb + M2;       // 4 MB
    ushort_t* ath = vtb + M2;      // 4 MB

    CastJobs jobs;
    jobs.in[0] = x;  jobs.hi[0] = xb;  jobs.n4[0] = (int)(M2 / 4);
    jobs.in[1] = wq; jobs.hi[1] = wqb; jobs.n4[1] = (int)(M1 / 4);
    jobs.in[2] = wk; jobs.hi[2] = wkb; jobs.n4[2] = (int)(M1 / 4);
    jobs.in[3] = wv; jobs.hi[3] = wvb; jobs.n4[3] = (int)(M1 / 4);
    jobs.in[4] = wo; jobs.hi[4] = wob; jobs.n4[4] = (int)(M1 / 4);
    cast_all_kernel<<<dim3(2048, 5), 256, 0, stream>>>(jobs);

    // fused QKV: single-wave 128x64 blocks, BK=64 dbuf, grid 48x16 = 768 blocks
    gemm_qkv_kernel<<<dim3(48, 16), 64, 0, stream>>>(
        xb, wqb, bq, wkb, bk_, wvb, bv, qb, kb, vtb);

    // V sums from vtb: 4096 waves, one per (n,h,d) row
    vsum_kernel<<<1024, 256, 0, stream>>>(vtb, vwin, vgwin);

    // attention: 1024 blocks (4/CU), 128 threads
    attn_mfma_kernel<<<dim3(16, NH, NW), 128, 0, stream>>>(
        qb, kb, vtb, vwin, vgwin, ath);

    // out projection: single-wave 64x64 blocks, BK=64 dbuf, grid 16x32 = 512 blocks
    gemm_out_kernel<<<dim3(16, 32), 64, 0, stream>>>(ath, wob, bo, out);
}